// Round 3
// baseline (17709.517 us; speedup 1.0000x reference)
//
#include <hip/hip_runtime.h>
#include <hip/hip_cooperative_groups.h>

namespace cg = cooperative_groups;

// LSTM S=512,B=128,I=H=1024. Round 5: persistent cooperative kernel.
// - Weights live in VGPRs (32 KB/wave = 128 VGPR), loaded ONCE for all 512 steps.
// - One grid.sync() per step (double-buffered packed h).
// - c state lives in a register per thread; hN/cN stored directly at the last step.
// gates_t = [h_t | x_t] @ [w_hh | w_ih]^T + bias  (K=2048, bf16 MFMA, fp32 acc)

#define S_LEN 512

using short8 = __attribute__((ext_vector_type(8))) short;  // 8 bf16 = one frag
using f32x4  = __attribute__((ext_vector_type(4))) float;

__device__ __forceinline__ unsigned short f2bf(float f) {
  unsigned int u = __float_as_uint(f);
  u += 0x7fffu + ((u >> 16) & 1u);   // RNE
  return (unsigned short)(u >> 16);
}
__device__ __forceinline__ unsigned int pk2(float a, float b) {
  return (unsigned int)f2bf(a) | ((unsigned int)f2bf(b) << 16);
}
__device__ __forceinline__ float sigf(float x)  { return 1.f / (1.f + __expf(-x)); }
__device__ __forceinline__ float tanhf_(float x){ return 2.f / (1.f + __expf(-2.f * x)) - 1.f; }

// ---- pack x: xp[t][rh2][kq4][ks8][rf4][ln64][8]  (a-frag order, bf16) ----
// a-frag mapping (16x16x32): row=lane&15, k=(lane>>4)*8+e
__global__ void xpack_kernel(const float* __restrict__ x, unsigned short* __restrict__ xp) {
  const int gid = blockIdx.x * 256 + threadIdx.x;     // 8,388,608 total
  const int t  = gid >> 14;
  const int u  = gid & 16383;
  const int ln = u & 63;
  const int u6 = u >> 6;            // (((rh*4+kq)*8+ks)*4+rf)
  const int rf = u6 & 3;
  const int ks = (u6 >> 2) & 7;
  const int kq = (u6 >> 5) & 3;
  const int rh = u6 >> 7;
  const int row = rh * 64 + rf * 16 + (ln & 15);
  const int i   = kq * 256 + ks * 32 + (ln >> 4) * 8;
  const float* src = x + ((size_t)t * 131072 + (size_t)row * 1024 + i);
  const float4 v0 = *(const float4*)src;
  const float4 v1 = *(const float4*)(src + 4);
  uint4 o;
  o.x = pk2(v0.x, v0.y); o.y = pk2(v0.z, v0.w);
  o.z = pk2(v1.x, v1.y); o.w = pk2(v1.z, v1.w);
  *(uint4*)(xp + (size_t)gid * 8) = o;
}

// ---- pack weights: wp[b64][kq8][ks8][cg4][ln64][8]  (b-frag order) ----
// fused K: kq<4 -> w_hh[k = kq*256+...], kq>=4 -> w_ih[k-1024]
__global__ void wpack_kernel(const float* __restrict__ w_hh, const float* __restrict__ w_ih,
                             unsigned short* __restrict__ wp) {
  const int gid = blockIdx.x * 256 + threadIdx.x;     // 1,048,576 total
  const int ln = gid & 63;
  const int u6 = gid >> 6;          // (((b*8+kq)*8+ks)*4+cg)
  const int cg = u6 & 3;
  const int ks = (u6 >> 2) & 7;
  const int kq = (u6 >> 5) & 7;
  const int b  = u6 >> 8;
  const int grow = cg * 1024 + b * 16 + (ln & 15);    // gate row
  const int k    = kq * 256 + ks * 32 + (ln >> 4) * 8;
  const float* src = (k < 1024) ? (w_hh + (size_t)grow * 1024 + k)
                                : (w_ih + (size_t)grow * 1024 + (k - 1024));
  const float4 v0 = *(const float4*)src;
  const float4 v1 = *(const float4*)(src + 4);
  uint4 o;
  o.x = pk2(v0.x, v0.y); o.y = pk2(v0.z, v0.w);
  o.z = pk2(v1.x, v1.y); o.w = pk2(v1.z, v1.w);
  *(uint4*)(wp + (size_t)gid * 8) = o;
}

__global__ void bias_sum_kernel(const float* __restrict__ a, const float* __restrict__ b,
                                float* __restrict__ o, int n) {
  int i = blockIdx.x * blockDim.x + threadIdx.x;
  if (i < n) o[i] = a[i] + b[i];
}

// ---- persistent LSTM ----
// grid 256 (1 block/CU): bid = rq*64 + b.  b -> h-cols [16b,16b+16) x 4 gates,
// rq -> batch rows [32rq, 32rq+32).  8 waves = 8-way K-split (256 K each);
// wave tile [32 rows x 64 gate-cols], weights for the wave's K-slice in VGPRs.
// Per step: A-frags streamed from L2, MFMA, f32x4 LDS reduce, fused epilogue,
// packed-h write, grid.sync().
__global__ __launch_bounds__(512, 2) void lstm_persist(
    const unsigned short* __restrict__ xp,      // packed x  [S][rh2][kq4][ks8][rf4][ln64][8]
    const unsigned short* __restrict__ wp,      // packed weights
    const float* __restrict__ bias,             // [4096]
    unsigned short* __restrict__ h0,            // packed h buffer (even t source)
    unsigned short* __restrict__ h1,            // packed h buffer (odd t source)
    float* __restrict__ out)                    // [S][128][1024] | hN | cN
{
  __shared__ f32x4 P[8][2][4][64];   // 64 KB: [kq][rf-frag][gate][lane]
  __shared__ f32x4 G[2][4][64];      // 8 KB: reduced gates
  const int tid  = threadIdx.x;
  const int lane = tid & 63;
  const int w    = tid >> 6;         // wave = kq 0..7
  const int rq   = blockIdx.x >> 6;  // row quarter 0..3
  const int b    = blockIdx.x & 63;  // h-col group
  const int rh   = rq >> 1;          // packed row-half
  const int rfb  = (rq & 1) * 2;     // rf base within the half
  const size_t aoff = (size_t)(rh * 4 + (w & 3)) * 16384;

  // ---- weights: once into registers (32 x short8 = 128 VGPR) ----
  const unsigned short* bb = wp + (size_t)(b * 8 + w) * 16384;
  short8 wreg[8][4];
#pragma unroll
  for (int ks = 0; ks < 8; ++ks)
#pragma unroll
    for (int cg = 0; cg < 4; ++cg)
      wreg[ks][cg] = *(const short8*)(bb + (ks * 4 + cg) * 512 + lane * 8);

  // ---- per-thread output cell (activation mapping), hoisted constants ----
  // tid = fr*256 + qc*64 + rc*16 + hc ; cell row = rq*32 + fr*16 + qc*4 + rc, col j = b*16+hc
  const int fr = tid >> 8;
  const int qc = (tid >> 6) & 3;
  const int rc = (tid >> 4) & 3;
  const int hc = tid & 15;
  const int j   = b * 16 + hc;
  const int row = rq * 32 + fr * 16 + qc * 4 + rc;
  const size_t idx = (size_t)row * 1024 + j;
  const float b0 = bias[j];
  const float b1 = bias[1024 + j];
  const float b2 = bias[2048 + j];
  const float b3 = bias[3072 + j];
  float creg = 0.f;                      // c state lives here for all 512 steps
  // packed-h write index (constant across t)
  const int kqm = j >> 8, ksj = (j >> 5) & 7, qj = (j >> 3) & 3, ej = j & 7;
  const int rhj = row >> 6, rfj = (row >> 4) & 3, rj = row & 15;
  const size_t hpk = (size_t)((((rhj * 4 + kqm) * 8 + ksj) * 4 + rfj) * 64 + (qj * 16 + rj)) * 8 + ej;
  const int gbase = (fr * 4) * 256 + (qc * 16 + hc) * 4 + rc;   // G float index, cg stride 256

  cg::grid_group grid = cg::this_grid();

  for (int t = 0; t < S_LEN; ++t) {
    const unsigned short* hin = (t & 1) ? h1 : h0;
    unsigned short*       hout = (t & 1) ? h0 : h1;
    const unsigned short* ab = ((w < 4) ? hin : (xp + (size_t)t * 131072)) + aoff;

    // ---- K-loop: 2-deep prefetch, 3-buffer rotation (static idx) ----
    short8 afr[3][2];
#pragma unroll
    for (int p = 0; p < 2; ++p)
#pragma unroll
      for (int f = 0; f < 2; ++f)
        afr[p][f] = *(const short8*)(ab + (p * 4 + rfb + f) * 512 + lane * 8);

    f32x4 acc[2][4] = {};
#pragma unroll
    for (int ks = 0; ks < 8; ++ks) {
      const int cur = ks % 3;
      if (ks < 6) {
        const int nxt = (ks + 2) % 3;
#pragma unroll
        for (int f = 0; f < 2; ++f)
          afr[nxt][f] = *(const short8*)(ab + ((ks + 2) * 4 + rfb + f) * 512 + lane * 8);
      }
#pragma unroll
      for (int f = 0; f < 2; ++f)
#pragma unroll
        for (int cg = 0; cg < 4; ++cg)
          acc[f][cg] = __builtin_amdgcn_mfma_f32_16x16x32_bf16(afr[cur][f], wreg[ks][cg], acc[f][cg], 0, 0, 0);
    }

    // ---- single-pass 8-way K reduction (f32x4, conflict-free) ----
#pragma unroll
    for (int f = 0; f < 2; ++f)
#pragma unroll
      for (int cg = 0; cg < 4; ++cg)
        P[w][f][cg][lane] = acc[f][cg];
    __syncthreads();
    {
      const int rf_e = w >> 2;      // 0..1
      const int cg_e = w & 3;       // 0..3
      f32x4 s = P[0][rf_e][cg_e][lane];
#pragma unroll
      for (int kq = 1; kq < 8; ++kq) s += P[kq][rf_e][cg_e][lane];
      G[rf_e][cg_e][lane] = s;
    }
    __syncthreads();

    // ---- fused activation + state update: one cell per thread ----
    const float* Gp = (const float*)G;
    const float g0 = Gp[gbase];
    const float g1 = Gp[gbase + 256];
    const float g2 = Gp[gbase + 512];
    const float g3 = Gp[gbase + 768];

    const float iv = sigf(g0 + b0);
    const float fv = sigf(g1 + b1);
    const float gv = tanhf_(g2 + b2);
    const float ov = sigf(g3 + b3);
    creg = fv * creg + iv * gv;
    const float hh = ov * tanhf_(creg);
    out[(size_t)t * 131072 + idx] = hh;
    hout[hpk] = f2bf(hh);
    if (t == S_LEN - 1) {
      out[(size_t)S_LEN * 131072 + idx] = hh;              // hN
      out[(size_t)S_LEN * 131072 + 131072 + idx] = creg;   // cN
    }

    if (t < S_LEN - 1) grid.sync();
  }
}

extern "C" void kernel_launch(void* const* d_in, const int* in_sizes, int n_in,
                              void* d_out, int out_size, void* d_ws, size_t ws_size,
                              hipStream_t stream) {
  (void)in_sizes; (void)n_in; (void)out_size; (void)ws_size;
  const float* x    = (const float*)d_in[0];
  const float* w_ih = (const float*)d_in[1];
  const float* w_hh = (const float*)d_in[2];
  const float* b_ih = (const float*)d_in[3];
  const float* b_hh = (const float*)d_in[4];
  float* out = (float*)d_out;

  char* ws = (char*)d_ws;
  const size_t XP_OFF   = 0;                        // 512*131072*2  = 134217728
  const size_t WP_OFF   = XP_OFF + 134217728;       // 1048576*16    =  16777216
  const size_t BIAS_OFF = WP_OFF + 16777216;        // 16384
  const size_t H0_OFF   = BIAS_OFF + 16384;         // 262144
  const size_t H1_OFF   = H0_OFF + 262144;          // 262144   (total ~152 MB)

  unsigned short* xp   = (unsigned short*)(ws + XP_OFF);
  unsigned short* wp   = (unsigned short*)(ws + WP_OFF);
  float*          bias = (float*)(ws + BIAS_OFF);
  unsigned short* h0   = (unsigned short*)(ws + H0_OFF);
  unsigned short* h1   = (unsigned short*)(ws + H1_OFF);

  xpack_kernel<<<32768, 256, 0, stream>>>(x, xp);
  wpack_kernel<<<4096, 256, 0, stream>>>(w_hh, w_ih, wp);
  bias_sum_kernel<<<16, 256, 0, stream>>>(b_ih, b_hh, bias, 4096);
  hipMemsetAsync(h0, 0, 262144, stream);

  void* args[] = {(void*)&xp, (void*)&wp, (void*)&bias, (void*)&h0, (void*)&h1, (void*)&out};
  hipLaunchCooperativeKernel((const void*)lstm_persist, dim3(256), dim3(512),
                             args, 0, stream);
}

// Round 4
// 4114.445 us; speedup vs baseline: 4.3042x; 4.3042x over previous
//
#include <hip/hip_runtime.h>

// LSTM S=512,B=128,I=H=1024. Round 6: revert to multi-launch (round-2 base),
// split the x-GEMM out of the recurrence.
//   gx[t] = x[t] @ w_ih^T + b_ih + b_hh   (chunked batched GEMM, 16 x 32 steps)
//   step:  gates = gx[t] + h @ w_hh^T     (K=1024 bf16 MFMA, fp32 acc)
// Workspace ~89 MB (< proven 152 MB budget).

#define S_LEN 512
#define CS 32            // chunk size (timesteps per pre-GEMM)
#define NCHUNK (S_LEN / CS)

using short8 = __attribute__((ext_vector_type(8))) short;  // 8 bf16 = one frag
using f32x4  = __attribute__((ext_vector_type(4))) float;

__device__ __forceinline__ unsigned short f2bf(float f) {
  unsigned int u = __float_as_uint(f);
  u += 0x7fffu + ((u >> 16) & 1u);   // RNE
  return (unsigned short)(u >> 16);
}
__device__ __forceinline__ unsigned int pk2(float a, float b) {
  return (unsigned int)f2bf(a) | ((unsigned int)f2bf(b) << 16);
}
__device__ __forceinline__ float sigf(float x)  { return 1.f / (1.f + __expf(-x)); }
__device__ __forceinline__ float tanhf_(float x){ return 2.f / (1.f + __expf(-2.f * x)) - 1.f; }

// ---- pack one chunk of x: xpc[tc][rh2][kk32][rf4][ln64][8]  (a-frag order) ----
// a-frag mapping (16x16x32): row=lane&15, k=(lane>>4)*8+e
__global__ void xpack_chunk(const float* __restrict__ x, unsigned short* __restrict__ xpc,
                            int t0) {
  const int gid = blockIdx.x * 256 + threadIdx.x;     // 524,288 total (32 t)
  const int tc = gid >> 14;
  const int u  = gid & 16383;
  const int ln = u & 63;
  const int u6 = u >> 6;            // ((rh*32+kk)*4+rf)
  const int rf = u6 & 3;
  const int kk = (u6 >> 2) & 31;
  const int rh = u6 >> 7;
  const int row = rh * 64 + rf * 16 + (ln & 15);
  const int i   = kk * 32 + (ln >> 4) * 8;
  const float* src = x + ((size_t)(t0 + tc) * 131072 + (size_t)row * 1024 + i);
  const float4 v0 = *(const float4*)src;
  const float4 v1 = *(const float4*)(src + 4);
  uint4 o;
  o.x = pk2(v0.x, v0.y); o.y = pk2(v0.z, v0.w);
  o.z = pk2(v1.x, v1.y); o.w = pk2(v1.z, v1.w);
  *(uint4*)(xpc + (size_t)gid * 8) = o;
}

// ---- pack a 4096x1024 weight matrix: wpk[b64][kk32][cg4][ln64][8] (b-frag order) ----
__global__ void wpack_kernel(const float* __restrict__ w, unsigned short* __restrict__ wpk) {
  const int gid = blockIdx.x * 256 + threadIdx.x;     // 524,288 total
  const int ln = gid & 63;
  const int u6 = gid >> 6;          // ((b*32+kk)*4+cg)
  const int cg = u6 & 3;
  const int kk = (u6 >> 2) & 31;
  const int b  = u6 >> 7;
  const int grow = cg * 1024 + b * 16 + (ln & 15);    // gate row
  const int k    = kk * 32 + (ln >> 4) * 8;
  const float* src = w + (size_t)grow * 1024 + k;
  const float4 v0 = *(const float4*)src;
  const float4 v1 = *(const float4*)(src + 4);
  uint4 o;
  o.x = pk2(v0.x, v0.y); o.y = pk2(v0.z, v0.w);
  o.z = pk2(v1.x, v1.y); o.w = pk2(v1.z, v1.w);
  *(uint4*)(wpk + (size_t)gid * 8) = o;
}

__global__ void bias_sum_kernel(const float* __restrict__ a, const float* __restrict__ b,
                                float* __restrict__ o, int n) {
  int i = blockIdx.x * blockDim.x + threadIdx.x;
  if (i < n) o[i] = a[i] + b[i];
}

// ---- chunk pre-GEMM: gxc[tc][gate4][row128][j1024] = x_t @ w_ih^T + bias ----
// grid 2048 = tc*64 + b (b = bid&63 keeps each weight slice XCD-local).
// 8 waves = 8-way row split (16 rows each), full K=1024 per wave, no reduction.
// B panel (128 KB) staged through LDS once, killing cross-wave L2 redundancy.
__global__ __launch_bounds__(512, 2) void pregemm_kernel(
    const unsigned short* __restrict__ xpc,   // packed x chunk
    const unsigned short* __restrict__ wi,    // packed w_ih
    const float* __restrict__ bias,           // [4096] (b_ih + b_hh)
    float* __restrict__ gxc)                  // [CS][4][128][1024] fp32
{
  __shared__ short Bs[65536];        // 128 KB: [kk32][cg4][ln64][8]
  const int tid  = threadIdx.x;
  const int lane = tid & 63;
  const int w    = tid >> 6;         // wave: row group 0..7
  const int tc   = blockIdx.x >> 6;
  const int b    = blockIdx.x & 63;

  // stage B: 128 frags of 1 KB; wave w loads frags [16w, 16w+16)
  {
    const unsigned short* wb = wi + (size_t)b * 65536;
#pragma unroll
    for (int i = 0; i < 16; ++i) {
      const int fi = w * 16 + i;
      *(short8*)&Bs[fi * 512 + lane * 8] = *(const short8*)(wb + (size_t)fi * 512 + lane * 8);
    }
  }
  __syncthreads();

  // A: rows [16w, 16w+16) => rh = w>>2, rf = w&3
  const int rh = w >> 2, rf = w & 3;
  const unsigned short* ab = xpc + (size_t)tc * 131072 + (size_t)(rh * 32 * 4 + rf) * 512;

  f32x4 acc[4] = {};
#pragma unroll
  for (int kk = 0; kk < 32; ++kk) {
    const short8 a = *(const short8*)(ab + (size_t)kk * 2048 + lane * 8);
#pragma unroll
    for (int cg = 0; cg < 4; ++cg) {
      const short8 bf = *(const short8*)&Bs[(kk * 4 + cg) * 512 + lane * 8];
      acc[cg] = __builtin_amdgcn_mfma_f32_16x16x32_bf16(a, bf, acc[cg], 0, 0, 0);
    }
  }

  // C/D layout: col = lane&15 (h-col within group), row = (lane>>4)*4 + r
  const int q   = lane >> 4;
  const int c15 = lane & 15;
  const int j   = b * 16 + c15;
#pragma unroll
  for (int cg = 0; cg < 4; ++cg) {
    const float bv = bias[cg * 1024 + j];
#pragma unroll
    for (int r = 0; r < 4; ++r) {
      const int row = w * 16 + q * 4 + r;
      gxc[(size_t)((tc * 4 + cg) * 128 + row) * 1024 + j] = acc[cg][r] + bv;
    }
  }
}

// ---- one LSTM step (K=1024, h @ w_hh^T only) ----
// grid 256: bid = rq*64 + b. b -> h-cols [16b,16b+16) x 4 gates, rq -> rows [32rq,32rq+32).
// 8 waves = 8-way K-split (128 K = 4 kk-frags each); wave tile [32 rows x 64 gate-cols].
// Single-pass f32x4 LDS reduction, one output cell per thread, gx added in epilogue.
__global__ __launch_bounds__(512, 2) void lstm_step(
    const unsigned short* __restrict__ hp_in,   // packed h  [rh2][kk32][rf4][ln64][8]
    const float* __restrict__ gx_t,             // [4][128][1024] fp32 (bias folded in)
    const unsigned short* __restrict__ wh,      // packed w_hh [b64][kk32][cg4][ln64][8]
    float* __restrict__ cbuf,                   // [128][1024] fp32
    float* __restrict__ out_t,                  // [128][1024] fp32
    unsigned short* __restrict__ hp_out)        // packed next h
{
  __shared__ f32x4 P[8][2][4][64];   // 64 KB: [kq][rf-frag][gate][lane]
  __shared__ f32x4 G[2][4][64];      // 8 KB: reduced gates
  const int tid  = threadIdx.x;
  const int lane = tid & 63;
  const int w    = tid >> 6;         // wave = K-slice 0..7 (kk in [4w,4w+4))
  const int rq   = blockIdx.x >> 6;  // row quarter 0..3
  const int b    = blockIdx.x & 63;  // h-col group
  const int rh   = rq >> 1;          // packed row-half
  const int rfb  = (rq & 1) * 2;     // rf base within the half

  // ---- per-thread output cell (activation mapping), hoisted loads ----
  // tid = fr*256 + qc*64 + rc*16 + hc ; cell row = rq*32 + fr*16 + qc*4 + rc, col j = b*16+hc
  const int fr = tid >> 8;
  const int qc = (tid >> 6) & 3;
  const int rc = (tid >> 4) & 3;
  const int hc = tid & 15;
  const int j   = b * 16 + hc;
  const int row = rq * 32 + fr * 16 + qc * 4 + rc;
  const size_t idx = (size_t)row * 1024 + j;
  const float gx0 = gx_t[(size_t)(0 * 128 + row) * 1024 + j];
  const float gx1 = gx_t[(size_t)(1 * 128 + row) * 1024 + j];
  const float gx2 = gx_t[(size_t)(2 * 128 + row) * 1024 + j];
  const float gx3 = gx_t[(size_t)(3 * 128 + row) * 1024 + j];
  const float cold = cbuf[idx];

  // ---- K-loop: 4 kk-frags, all loads up-front, then 32 MFMA ----
  const unsigned short* ab = hp_in + (size_t)(rh * 32 + w * 4) * 2048;
  const unsigned short* bb = wh + (size_t)(b * 32 + w * 4) * 2048;

  short8 afr[4][2], bfr[4][4];
#pragma unroll
  for (int s = 0; s < 4; ++s) {
#pragma unroll
    for (int f = 0; f < 2; ++f)
      afr[s][f] = *(const short8*)(ab + (size_t)(s * 4 + rfb + f) * 512 + lane * 8);
#pragma unroll
    for (int cg = 0; cg < 4; ++cg)
      bfr[s][cg] = *(const short8*)(bb + (size_t)(s * 4 + cg) * 512 + lane * 8);
  }

  f32x4 acc[2][4] = {};
#pragma unroll
  for (int s = 0; s < 4; ++s)
#pragma unroll
    for (int f = 0; f < 2; ++f)
#pragma unroll
      for (int cg = 0; cg < 4; ++cg)
        acc[f][cg] = __builtin_amdgcn_mfma_f32_16x16x32_bf16(afr[s][f], bfr[s][cg], acc[f][cg], 0, 0, 0);

  // ---- single-pass 8-way K reduction (f32x4, conflict-free) ----
#pragma unroll
  for (int f = 0; f < 2; ++f)
#pragma unroll
    for (int cg = 0; cg < 4; ++cg)
      P[w][f][cg][lane] = acc[f][cg];
  __syncthreads();
  {
    const int rf_e = w >> 2;      // 0..1
    const int cg_e = w & 3;       // 0..3
    f32x4 s = P[0][rf_e][cg_e][lane];
#pragma unroll
    for (int kq = 1; kq < 8; ++kq) s += P[kq][rf_e][cg_e][lane];
    G[rf_e][cg_e][lane] = s;
  }
  __syncthreads();

  // ---- fused activation + state update: one cell per thread ----
  const float* Gp = (const float*)G;
  const int gbase = (fr * 4) * 256 + (qc * 16 + hc) * 4 + rc;   // float index, cg stride 256
  const float iv = sigf(Gp[gbase]       + gx0);
  const float fv = sigf(Gp[gbase + 256] + gx1);
  const float gv = tanhf_(Gp[gbase + 512] + gx2);
  const float ov = sigf(Gp[gbase + 768] + gx3);
  const float cc = fv * cold + iv * gv;
  cbuf[idx] = cc;
  const float hh = ov * tanhf_(cc);
  out_t[idx] = hh;
  // write next h in packed a-frag order
  const int kkj = j >> 5, qj = (j >> 3) & 3, ej = j & 7;
  const int rhj = row >> 6, rfj = (row >> 4) & 3, rj = row & 15;
  hp_out[(size_t)(((rhj * 32 + kkj) * 4 + rfj) * 64 + (qj * 16 + rj)) * 8 + ej] = f2bf(hh);
}

extern "C" void kernel_launch(void* const* d_in, const int* in_sizes, int n_in,
                              void* d_out, int out_size, void* d_ws, size_t ws_size,
                              hipStream_t stream) {
  (void)in_sizes; (void)n_in; (void)out_size; (void)ws_size;
  const float* x    = (const float*)d_in[0];
  const float* w_ih = (const float*)d_in[1];
  const float* w_hh = (const float*)d_in[2];
  const float* b_ih = (const float*)d_in[3];
  const float* b_hh = (const float*)d_in[4];
  float* out = (float*)d_out;

  char* ws = (char*)d_ws;
  const size_t XPC_OFF  = 0;                         // 32*131072*2   =   8,388,608
  const size_t GXC_OFF  = XPC_OFF + 8388608;         // 32*4*128*1024*4 = 67,108,864
  const size_t WH_OFF   = GXC_OFF + 67108864;        // 524288*16     =   8,388,608
  const size_t WI_OFF   = WH_OFF + 8388608;          //                   8,388,608
  const size_t BIAS_OFF = WI_OFF + 8388608;          // 16,384
  const size_t C_OFF    = BIAS_OFF + 16384;          // 524,288
  const size_t H0_OFF   = C_OFF + 524288;            // 262,144
  const size_t H1_OFF   = H0_OFF + 262144;           // 262,144   (total ~89 MB)

  unsigned short* xpc  = (unsigned short*)(ws + XPC_OFF);
  float*          gxc  = (float*)(ws + GXC_OFF);
  unsigned short* wh   = (unsigned short*)(ws + WH_OFF);
  unsigned short* wi   = (unsigned short*)(ws + WI_OFF);
  float*          bias = (float*)(ws + BIAS_OFF);
  float*          cbuf = (float*)(ws + C_OFF);
  unsigned short* h0   = (unsigned short*)(ws + H0_OFF);
  unsigned short* h1   = (unsigned short*)(ws + H1_OFF);

  wpack_kernel<<<2048, 256, 0, stream>>>(w_hh, wh);
  wpack_kernel<<<2048, 256, 0, stream>>>(w_ih, wi);
  bias_sum_kernel<<<16, 256, 0, stream>>>(b_ih, b_hh, bias, 4096);
  hipMemsetAsync(cbuf, 0, 524288, stream);
  hipMemsetAsync(h0, 0, 262144, stream);

  unsigned short* hin = h0;
  unsigned short* hout = h1;
  for (int c = 0; c < NCHUNK; ++c) {
    const int t0 = c * CS;
    xpack_chunk<<<2048, 256, 0, stream>>>(x, xpc, t0);
    pregemm_kernel<<<2048, 512, 0, stream>>>(xpc, wi, bias, gxc);
    for (int s = 0; s < CS; ++s) {
      const int t = t0 + s;
      lstm_step<<<256, 512, 0, stream>>>(hin, gxc + (size_t)s * 524288, wh, cbuf,
                                         out + (size_t)t * 131072, hout);
      unsigned short* tmp = hin; hin = hout; hout = tmp;
    }
  }

  // outputs: [S,B,H] | hN | cN
  hipMemcpyAsync(out + (size_t)S_LEN * 131072, out + (size_t)(S_LEN - 1) * 131072,
                 131072 * sizeof(float), hipMemcpyDeviceToDevice, stream);
  hipMemcpyAsync(out + (size_t)S_LEN * 131072 + 131072, cbuf,
                 131072 * sizeof(float), hipMemcpyDeviceToDevice, stream);
}